// Round 2
// baseline (504.569 us; speedup 1.0000x reference)
//
#include <hip/hip_runtime.h>

#define BB 16
#define TT 1024
#define DD 512
#define VV 256
#define MM (BB*TT)

#define DPINF 1e30f

// DPP min-reduce step (row_shr within 16-lane rows); old = same reg -> identity for OOB lanes
#define DPP_MIN_STEP(m, CTRL) { \
  int _t = __builtin_amdgcn_update_dpp(__float_as_int(m), __float_as_int(m), CTRL, 0xF, 0xF, false); \
  m = fminf(m, __int_as_float(_t)); }

// ---------------------------------------------------------------------------
// Kernel 1: row norms of reps (r2[16384]) and codebook (c2[256]); 1 wave/row
// ---------------------------------------------------------------------------
__global__ __launch_bounds__(256) void norms_k(const float* __restrict__ reps,
                                               const float* __restrict__ cb,
                                               float* __restrict__ r2,
                                               float* __restrict__ c2) {
  int row = blockIdx.x * 4 + (threadIdx.x >> 6);
  int lane = threadIdx.x & 63;
  const float* src;
  float* dst;
  if (row < MM) {
    src = reps + (size_t)row * DD;
    dst = r2 + row;
  } else {
    int r = row - MM;
    if (r >= VV) return;
    src = cb + (size_t)r * DD;
    dst = c2 + r;
  }
  const float4* s4 = (const float4*)src;
  float4 a = s4[lane];
  float4 b = s4[lane + 64];
  float s = a.x*a.x + a.y*a.y + a.z*a.z + a.w*a.w
          + b.x*b.x + b.y*b.y + b.z*b.z + b.w*b.w;
#pragma unroll
  for (int off = 1; off < 64; off <<= 1) s += __shfl_xor(s, off);
  if (lane == 0) *dst = s;
}

// ---------------------------------------------------------------------------
// Kernel 2: d[m][v] = r2[m] - 2*dot(reps[m], cb[v]) + c2[v]
// fp32 tiled GEMM: 64x64 tile, BK=32, 256 threads, 4x4 micro-tile
// ---------------------------------------------------------------------------
__global__ __launch_bounds__(256) void gemm_k(const float* __restrict__ reps,
                                              const float* __restrict__ cb,
                                              const float* __restrict__ r2,
                                              const float* __restrict__ c2,
                                              float* __restrict__ dmat) {
  __shared__ __align__(16) float As[32][68];
  __shared__ __align__(16) float Bs[32][68];
  int tid = threadIdx.x;
  int m0 = blockIdx.y * 64, n0 = blockIdx.x * 64;
  int tx = tid & 15, ty = tid >> 4;
  int lrow = tid >> 3, lcol = tid & 7;
  float acc[4][4] = {{0.f}};
  const float* arow0 = reps + (size_t)(m0 + lrow) * DD + lcol * 4;
  const float* arow1 = arow0 + (size_t)32 * DD;
  const float* brow0 = cb + (size_t)(n0 + lrow) * DD + lcol * 4;
  const float* brow1 = brow0 + (size_t)32 * DD;

  for (int k0 = 0; k0 < DD; k0 += 32) {
    float4 a0 = *(const float4*)(arow0 + k0);
    float4 a1 = *(const float4*)(arow1 + k0);
    float4 b0 = *(const float4*)(brow0 + k0);
    float4 b1 = *(const float4*)(brow1 + k0);
    __syncthreads();
    int kc = lcol * 4;
    As[kc+0][lrow] = a0.x; As[kc+1][lrow] = a0.y; As[kc+2][lrow] = a0.z; As[kc+3][lrow] = a0.w;
    As[kc+0][lrow+32] = a1.x; As[kc+1][lrow+32] = a1.y; As[kc+2][lrow+32] = a1.z; As[kc+3][lrow+32] = a1.w;
    Bs[kc+0][lrow] = b0.x; Bs[kc+1][lrow] = b0.y; Bs[kc+2][lrow] = b0.z; Bs[kc+3][lrow] = b0.w;
    Bs[kc+0][lrow+32] = b1.x; Bs[kc+1][lrow+32] = b1.y; Bs[kc+2][lrow+32] = b1.z; Bs[kc+3][lrow+32] = b1.w;
    __syncthreads();
#pragma unroll
    for (int kk = 0; kk < 32; ++kk) {
      float4 av = *(const float4*)&As[kk][ty * 4];
      float4 bv = *(const float4*)&Bs[kk][tx * 4];
      float aa[4] = {av.x, av.y, av.z, av.w};
      float bb[4] = {bv.x, bv.y, bv.z, bv.w};
#pragma unroll
      for (int i = 0; i < 4; ++i)
#pragma unroll
        for (int j = 0; j < 4; ++j)
          acc[i][j] += aa[i] * bb[j];
    }
  }

  int gm = m0 + ty * 4, gn = n0 + tx * 4;
  float cc[4] = {c2[gn], c2[gn+1], c2[gn+2], c2[gn+3]};
#pragma unroll
  for (int i = 0; i < 4; ++i) {
    float rv = r2[gm + i];
    float4 o;
    o.x = fmaf(-2.f, acc[i][0], rv + cc[0]);
    o.y = fmaf(-2.f, acc[i][1], rv + cc[1]);
    o.z = fmaf(-2.f, acc[i][2], rv + cc[2]);
    o.w = fmaf(-2.f, acc[i][3], rv + cc[3]);
    *(float4*)&dmat[(size_t)(gm + i) * VV + gn] = o;
  }
}

// ---------------------------------------------------------------------------
// Kernel 3: W[t][i] = min_v sum_{f=s+1..t} d[f][v],  A = argmin_v (first-min),
// where s = t-64+i. Block = one batch b x 64 consecutive t's.
// Window-local cumsum in LDS (no global C needed); v processed in 2 halves
// of 128 so LDS = 128 rows x 128 cols x 4B = 64KB static.
// ---------------------------------------------------------------------------
__global__ __launch_bounds__(256) void w_k(const float* __restrict__ dmat,
                                           float2* __restrict__ WA) {
  __shared__ __align__(16) float CL[128 * 128];
  int b = blockIdx.x >> 4;
  int chunk = blockIdx.x & 15;
  int t1 = 1 + (chunk << 6);             // block covers t in [t1, t1+63]
  int tid = threadIdx.x;
  int wv = tid >> 6, lane = tid & 63;

  float bw[16];
  int ba[16];
#pragma unroll
  for (int j = 0; j < 16; ++j) { bw[j] = 1e38f; ba[j] = 0; }

  for (int half = 0; half < 2; ++half) {
    __syncthreads();   // protect CL from previous half's readers
    if (tid < 32) {
      int g = tid;     // float4 group 0..31 within this v-half
      float4 c = make_float4(0.f, 0.f, 0.f, 0.f);
      *(float4*)&CL[0 * 128 + (g << 2)] = c;          // k=0: swz g^0=g
      for (int k = 1; k <= 127; ++k) {
        int f = t1 - 64 + k;                           // frame number
        if (f >= 1 && f <= TT) {
          float4 dv = *(const float4*)&dmat[((size_t)b * TT + (f - 1)) * VV + (half << 7) + (g << 2)];
          c.x += dv.x; c.y += dv.y; c.z += dv.z; c.w += dv.w;
        }
        *(float4*)&CL[k * 128 + ((g ^ (k & 31)) << 2)] = c;
      }
    }
    __syncthreads();

#pragma unroll
    for (int j = 0; j < 16; ++j) {
      int dt = (j << 2) + wv;           // 0..63
      int ks = dt + lane;               // row of C_s (s = t-64+lane)
      int kt = dt + 64;                 // row of C_t
      const float* rs = &CL[ks * 128];
      const float* rt = &CL[kt * 128];
      int ksm = ks & 31, ktm = kt & 31;
      float bv = bw[j];
      int bi = ba[j];
#pragma unroll 4
      for (int g = 0; g < 32; ++g) {
        float4 a = *(const float4*)&rs[(g ^ ksm) << 2];
        float4 t4 = *(const float4*)&rt[(g ^ ktm) << 2];
        int v0 = (half << 7) + (g << 2);
        float s0 = t4.x - a.x; if (s0 < bv) { bv = s0; bi = v0; }
        float s1 = t4.y - a.y; if (s1 < bv) { bv = s1; bi = v0 + 1; }
        float s2 = t4.z - a.z; if (s2 < bv) { bv = s2; bi = v0 + 2; }
        float s3 = t4.w - a.w; if (s3 < bv) { bv = s3; bi = v0 + 3; }
      }
      bw[j] = bv; ba[j] = bi;
    }
  }

#pragma unroll
  for (int j = 0; j < 16; ++j) {
    int t = t1 + (j << 2) + wv;
    WA[((size_t)b * TT + (t - 1)) * 64 + lane] = make_float2(bw[j], __int_as_float(ba[j]));
  }
}

// ---------------------------------------------------------------------------
// Kernel 4: sequential DP + backtrack + output. One wave per batch.
// Lane l statically holds costs[s] for s == l (mod 64); per step:
// rotated W-row load (4-deep prefetch), DPP/shfl min-reduce, ballot argmin.
// OUTPUT ENCODING: harness reads d_out as float32 -> write float values.
// ---------------------------------------------------------------------------
__global__ __launch_bounds__(64) void dp_k(const float2* __restrict__ WA,
                                           const int* __restrict__ lengths,
                                           float* __restrict__ out) {
  int b = blockIdx.x;
  int lane = threadIdx.x;
  __shared__ float2 arr[TT + 1];   // (cost, packed prev<<8|tok)
  __shared__ int bs[TT];
  __shared__ int ts[TT];

  const float2* Wb = WA + (size_t)b * TT * 64;
  float cs = (lane == 0) ? 0.f : DPINF;
  if (lane == 0) arr[0] = make_float2(0.f, 0.f);
  float m_keep;

  auto rowload = [&](int tt) -> float2 {
    int cr = (tt <= TT) ? (tt - 1) : (TT - 1);
    return Wb[cr * 64 + ((lane - tt) & 63)];
  };

  auto step = [&](int t, float2 cur) {
    int i = (lane - t) & 63;          // s = t-64+i
    bool valid = (i >= 64 - t);       // s >= 0 (s<t always)
    float total = valid ? (cs + cur.x) : DPINF;
    float m = total;
    DPP_MIN_STEP(m, 0x111);           // row_shr:1
    DPP_MIN_STEP(m, 0x112);           // row_shr:2
    DPP_MIN_STEP(m, 0x114);           // row_shr:4
    DPP_MIN_STEP(m, 0x118);           // row_shr:8
    m = fminf(m, __shfl_xor(m, 16));
    m = fminf(m, __shfl_xor(m, 32));
    float mf = __int_as_float(__builtin_amdgcn_readlane(__float_as_int(m), 63));
    unsigned long long msk = __ballot(total == mf);
    int r = t & 63;
    unsigned long long rot = r ? ((msk >> r) | (msk << (64 - r))) : msk;
    int iwin = __builtin_ctzll(rot);                  // smallest i => smallest s (ref tie-break)
    int lwin = (iwin + r) & 63;
    int tokw = __builtin_amdgcn_readlane(__float_as_int(cur.y), lwin) & 255;
    unsigned packed = ((unsigned)(t - 64 + iwin) << 8) | (unsigned)tokw;
    if (lane == 0) arr[t] = make_float2(mf, __uint_as_float(packed));
    cs = (lane == r) ? mf : cs;       // lane (t&63) now holds costs[t]
    m_keep = mf;
  };

  float2 p0 = rowload(1), p1 = rowload(2), p2 = rowload(3), p3 = rowload(4);
  for (int t = 1; t <= TT; t += 4) {
    float2 n0 = rowload(t + 4);
    float2 n1 = rowload(t + 5);
    float2 n2 = rowload(t + 6);
    float2 n3 = rowload(t + 7);
    step(t, p0);
    step(t + 1, p1);
    step(t + 2, p2);
    step(t + 3, p3);
    p0 = n0; p1 = n1; p2 = n2; p3 = n3;
  }
  (void)m_keep;
  __syncthreads();

  // backtrack (lane 0 serial walk over LDS)
  int len = lengths[b];
  len = (len > TT) ? TT : (len < 0 ? 0 : len);
  int cnt = 0;
  if (lane == 0) {
    int st = len;
    while (st > 0 && cnt < TT) {
      float2 e = arr[st];
      unsigned p = __float_as_uint(e.y);
      bs[cnt] = st;
      ts[cnt] = (int)(p & 255u);
      st = (int)(p >> 8);
      ++cnt;
    }
  }
  cnt = __shfl(cnt, 0);
  __syncthreads();

  // float32-encoded outputs (harness reads whole d_out as float32)
  float* bout = out + b * TT;
  float* tout = out + MM + b * TT;
  for (int k = lane; k < TT; k += 64) {
    bout[k] = (k < cnt) ? (float)bs[cnt - 1 - k] : 0.f;
    tout[k] = (k < cnt) ? (float)ts[cnt - 1 - k] : 0.f;
  }
  if (lane == 0) {
    out[2 * MM + b] = (float)cnt;           // counts
    out[2 * MM + BB + b] = arr[len].x;      // final cost (float)
  }
}

// ---------------------------------------------------------------------------
extern "C" void kernel_launch(void* const* d_in, const int* in_sizes, int n_in,
                              void* d_out, int out_size, void* d_ws, size_t ws_size,
                              hipStream_t stream) {
  const float* reps = (const float*)d_in[0];
  const float* cb   = (const float*)d_in[1];
  const int* lengths = (const int*)d_in[2];
  float* out = (float*)d_out;

  char* ws = (char*)d_ws;
  float* r2 = (float*)ws;                                   // 64 KB
  float* c2 = (float*)(ws + 65536);                         // 4 KB slot
  float* dmat = (float*)(ws + 69632);                       // 16 MB
  float2* WA = (float2*)(ws + 69632 + (size_t)MM * VV * 4); // 8 MB

  norms_k<<<(MM + VV) / 4, 256, 0, stream>>>(reps, cb, r2, c2);
  gemm_k<<<dim3(VV / 64, MM / 64), 256, 0, stream>>>(reps, cb, r2, c2, dmat);
  w_k<<<BB * (TT / 64), 256, 0, stream>>>(dmat, WA);
  dp_k<<<BB, 64, 0, stream>>>(WA, lengths, out);
}

// Round 3
// 418.677 us; speedup vs baseline: 1.2052x; 1.2052x over previous
//
#include <hip/hip_runtime.h>

#define BB 16
#define TT 1024
#define DD 512
#define VV 256
#define MM (BB*TT)

#define DPINF 1e30f

// DPP min-reduce step; old = same reg -> identity for lanes with no source
#define DPP_MIN_STEP(m, CTRL) { \
  int _t = __builtin_amdgcn_update_dpp(__float_as_int(m), __float_as_int(m), CTRL, 0xF, 0xF, false); \
  m = fminf(m, __int_as_float(_t)); }

// full 64-lane min into lane 63: row_shr 1,2,4,8 then row_bcast15, row_bcast31
#define DPP_MIN_REDUCE(m) \
  DPP_MIN_STEP(m, 0x111); DPP_MIN_STEP(m, 0x112); DPP_MIN_STEP(m, 0x114); \
  DPP_MIN_STEP(m, 0x118); DPP_MIN_STEP(m, 0x142); DPP_MIN_STEP(m, 0x143);

// ---------------------------------------------------------------------------
// Kernel 1: row norms of reps (r2[16384]) and codebook (c2[256]); 1 wave/row
// ---------------------------------------------------------------------------
__global__ __launch_bounds__(256) void norms_k(const float* __restrict__ reps,
                                               const float* __restrict__ cb,
                                               float* __restrict__ r2,
                                               float* __restrict__ c2) {
  int row = blockIdx.x * 4 + (threadIdx.x >> 6);
  int lane = threadIdx.x & 63;
  const float* src;
  float* dst;
  if (row < MM) {
    src = reps + (size_t)row * DD;
    dst = r2 + row;
  } else {
    int r = row - MM;
    if (r >= VV) return;
    src = cb + (size_t)r * DD;
    dst = c2 + r;
  }
  const float4* s4 = (const float4*)src;
  float4 a = s4[lane];
  float4 b = s4[lane + 64];
  float s = a.x*a.x + a.y*a.y + a.z*a.z + a.w*a.w
          + b.x*b.x + b.y*b.y + b.z*b.z + b.w*b.w;
#pragma unroll
  for (int off = 1; off < 64; off <<= 1) s += __shfl_xor(s, off);
  if (lane == 0) *dst = s;
}

// ---------------------------------------------------------------------------
// Kernel 2: d[m][v] = r2[m] - 2*dot(reps[m], cb[v]) + c2[v]
// fp32 tiled GEMM: 64x64 tile, BK=32, 256 threads, 4x4 micro-tile
// ---------------------------------------------------------------------------
__global__ __launch_bounds__(256) void gemm_k(const float* __restrict__ reps,
                                              const float* __restrict__ cb,
                                              const float* __restrict__ r2,
                                              const float* __restrict__ c2,
                                              float* __restrict__ dmat) {
  __shared__ __align__(16) float As[32][68];
  __shared__ __align__(16) float Bs[32][68];
  int tid = threadIdx.x;
  int m0 = blockIdx.y * 64, n0 = blockIdx.x * 64;
  int tx = tid & 15, ty = tid >> 4;
  int lrow = tid >> 3, lcol = tid & 7;
  float acc[4][4] = {{0.f}};
  const float* arow0 = reps + (size_t)(m0 + lrow) * DD + lcol * 4;
  const float* arow1 = arow0 + (size_t)32 * DD;
  const float* brow0 = cb + (size_t)(n0 + lrow) * DD + lcol * 4;
  const float* brow1 = brow0 + (size_t)32 * DD;

  for (int k0 = 0; k0 < DD; k0 += 32) {
    float4 a0 = *(const float4*)(arow0 + k0);
    float4 a1 = *(const float4*)(arow1 + k0);
    float4 b0 = *(const float4*)(brow0 + k0);
    float4 b1 = *(const float4*)(brow1 + k0);
    __syncthreads();
    int kc = lcol * 4;
    As[kc+0][lrow] = a0.x; As[kc+1][lrow] = a0.y; As[kc+2][lrow] = a0.z; As[kc+3][lrow] = a0.w;
    As[kc+0][lrow+32] = a1.x; As[kc+1][lrow+32] = a1.y; As[kc+2][lrow+32] = a1.z; As[kc+3][lrow+32] = a1.w;
    Bs[kc+0][lrow] = b0.x; Bs[kc+1][lrow] = b0.y; Bs[kc+2][lrow] = b0.z; Bs[kc+3][lrow] = b0.w;
    Bs[kc+0][lrow+32] = b1.x; Bs[kc+1][lrow+32] = b1.y; Bs[kc+2][lrow+32] = b1.z; Bs[kc+3][lrow+32] = b1.w;
    __syncthreads();
#pragma unroll
    for (int kk = 0; kk < 32; ++kk) {
      float4 av = *(const float4*)&As[kk][ty * 4];
      float4 bv = *(const float4*)&Bs[kk][tx * 4];
      float aa[4] = {av.x, av.y, av.z, av.w};
      float bb[4] = {bv.x, bv.y, bv.z, bv.w};
#pragma unroll
      for (int i = 0; i < 4; ++i)
#pragma unroll
        for (int j = 0; j < 4; ++j)
          acc[i][j] += aa[i] * bb[j];
    }
  }

  int gm = m0 + ty * 4, gn = n0 + tx * 4;
  float cc[4] = {c2[gn], c2[gn+1], c2[gn+2], c2[gn+3]};
#pragma unroll
  for (int i = 0; i < 4; ++i) {
    float rv = r2[gm + i];
    float4 o;
    o.x = fmaf(-2.f, acc[i][0], rv + cc[0]);
    o.y = fmaf(-2.f, acc[i][1], rv + cc[1]);
    o.z = fmaf(-2.f, acc[i][2], rv + cc[2]);
    o.w = fmaf(-2.f, acc[i][3], rv + cc[3]);
    *(float4*)&dmat[(size_t)(gm + i) * VV + gn] = o;
  }
}

// ---------------------------------------------------------------------------
// Kernel 3: W[t][i] = min_v sum_{f=s+1..t} d[f][v],  A = argmin_v (first-min),
// s = t-64+i. Window-local cumsum in LDS; v in 2 halves of 128 (64KB LDS).
// Outputs split: Wv (float) for the sequential DP, WI (u8 token) for prev_k.
// ---------------------------------------------------------------------------
__global__ __launch_bounds__(256) void w_k(const float* __restrict__ dmat,
                                           float* __restrict__ Wv,
                                           unsigned char* __restrict__ WI) {
  __shared__ __align__(16) float CL[128 * 128];
  int b = blockIdx.x >> 4;
  int chunk = blockIdx.x & 15;
  int t1 = 1 + (chunk << 6);             // block covers t in [t1, t1+63]
  int tid = threadIdx.x;
  int wv = tid >> 6, lane = tid & 63;

  float bw[16];
  int ba[16];
#pragma unroll
  for (int j = 0; j < 16; ++j) { bw[j] = 1e38f; ba[j] = 0; }

  for (int half = 0; half < 2; ++half) {
    __syncthreads();   // protect CL from previous half's readers
    if (tid < 32) {
      int g = tid;     // float4 group 0..31 within this v-half
      float4 c = make_float4(0.f, 0.f, 0.f, 0.f);
      *(float4*)&CL[0 * 128 + (g << 2)] = c;          // k=0: swz g^0=g
      for (int k = 1; k <= 127; ++k) {
        int f = t1 - 64 + k;                           // frame number
        if (f >= 1 && f <= TT) {
          float4 dv = *(const float4*)&dmat[((size_t)b * TT + (f - 1)) * VV + (half << 7) + (g << 2)];
          c.x += dv.x; c.y += dv.y; c.z += dv.z; c.w += dv.w;
        }
        *(float4*)&CL[k * 128 + ((g ^ (k & 31)) << 2)] = c;
      }
    }
    __syncthreads();

#pragma unroll
    for (int j = 0; j < 16; ++j) {
      int dt = (j << 2) + wv;           // 0..63
      int ks = dt + lane;               // row of C_s (s = t-64+lane)
      int kt = dt + 64;                 // row of C_t
      const float* rs = &CL[ks * 128];
      const float* rt = &CL[kt * 128];
      int ksm = ks & 31, ktm = kt & 31;
      float bv = bw[j];
      int bi = ba[j];
#pragma unroll 4
      for (int g = 0; g < 32; ++g) {
        float4 a = *(const float4*)&rs[(g ^ ksm) << 2];
        float4 t4 = *(const float4*)&rt[(g ^ ktm) << 2];
        int v0 = (half << 7) + (g << 2);
        float s0 = t4.x - a.x; if (s0 < bv) { bv = s0; bi = v0; }
        float s1 = t4.y - a.y; if (s1 < bv) { bv = s1; bi = v0 + 1; }
        float s2 = t4.z - a.z; if (s2 < bv) { bv = s2; bi = v0 + 2; }
        float s3 = t4.w - a.w; if (s3 < bv) { bv = s3; bi = v0 + 3; }
      }
      bw[j] = bv; ba[j] = bi;
    }
  }

#pragma unroll
  for (int j = 0; j < 16; ++j) {
    int t = t1 + (j << 2) + wv;
    size_t idx = ((size_t)b * TT + (t - 1)) * 64 + lane;
    Wv[idx] = bw[j];
    WI[idx] = (unsigned char)ba[j];
  }
}

// ---------------------------------------------------------------------------
// Kernel 4a: sequential DP, min VALUE only (argmin deferred to prev_k).
// One wave per batch. Lane l holds costs[s] for s == l (mod 64). Per step:
// add -> 6 dependent DPP mins (all-VALU reduce into lane 63) -> readlane ->
// cndmask. No LDS, no ballot, no shfl in the chain. 8-deep row prefetch.
// Lanes for s<0 hold 1e30; 1e30+w dominates any real total, so no validity
// mask needed.
// ---------------------------------------------------------------------------
__global__ __launch_bounds__(64) void dp_seq(const float* __restrict__ Wv,
                                             float* __restrict__ cg) {
  int b = blockIdx.x;
  int lane = threadIdx.x;
  const float* Wb = Wv + (size_t)b * TT * 64;
  float* cgb = cg + (size_t)b * (TT + 1);
  float cs = (lane == 0) ? 0.f : DPINF;
  if (lane == 0) cgb[0] = 0.f;

  auto rowload = [&](int tt) -> float {
    int cr = (tt <= TT) ? (tt - 1) : (TT - 1);
    return Wb[cr * 64 + ((lane - tt) & 63)];
  };

  auto step = [&](int t, float w) {
    float m = cs + w;
    DPP_MIN_REDUCE(m);
    float mf = __int_as_float(__builtin_amdgcn_readlane(__float_as_int(m), 63));
    if (lane == 63) cgb[t] = m;        // lane 63 holds the full min in VGPR
    cs = (lane == (t & 63)) ? mf : cs; // lane (t&63) now holds costs[t]
  };

  float a0 = rowload(1), a1 = rowload(2), a2 = rowload(3), a3 = rowload(4);
  float a4 = rowload(5), a5 = rowload(6), a6 = rowload(7), a7 = rowload(8);
  for (int t = 1; t <= TT; t += 4) {
    float n0 = rowload(t + 8);
    float n1 = rowload(t + 9);
    float n2 = rowload(t + 10);
    float n3 = rowload(t + 11);
    step(t, a0);
    step(t + 1, a1);
    step(t + 2, a2);
    step(t + 3, a3);
    a0 = a4; a1 = a5; a2 = a6; a3 = a7;
    a4 = n0; a5 = n1; a6 = n2; a7 = n3;
  }
}

// ---------------------------------------------------------------------------
// Kernel 4b: parallel argmin. One wave per t: recompute total = cg[s]+W[t][i]
// (bit-identical to the sums dp_seq reduced), find first-min -> prev, tok.
// ---------------------------------------------------------------------------
__global__ __launch_bounds__(256) void prev_k(const float* __restrict__ Wv,
                                              const unsigned char* __restrict__ WI,
                                              const float* __restrict__ cg,
                                              int* __restrict__ pk) {
  int row = blockIdx.x * 4 + (threadIdx.x >> 6);   // row in [0, BB*TT)
  int lane = threadIdx.x & 63;
  int b = row >> 10;
  int t = (row & 1023) + 1;
  int s = t - 64 + lane;
  size_t idx = (size_t)row * 64 + lane;
  float w = Wv[idx];
  int wi = WI[idx];
  int sc = (s < 0) ? 0 : s;
  float c = cg[(size_t)b * (TT + 1) + sc];
  float total = (s >= 0) ? (c + w) : DPINF;
  float m = total;
  DPP_MIN_REDUCE(m);
  float mf = __int_as_float(__builtin_amdgcn_readlane(__float_as_int(m), 63));
  unsigned long long msk = __ballot(total == mf);
  int iwin = __builtin_ctzll(msk);                 // smallest i = smallest s (ref tie-break)
  int tok = __builtin_amdgcn_readlane(wi, iwin) & 255;
  int prev = t - 64 + iwin;
  if (lane == 0) pk[(size_t)b * (TT + 1) + t] = (prev << 8) | tok;
}

// ---------------------------------------------------------------------------
// Kernel 4c: backtrack + outputs. One wave per batch; packed prev/tok walk
// in LDS; float32-encoded outputs (harness reads whole d_out as float32).
// ---------------------------------------------------------------------------
__global__ __launch_bounds__(64) void bt_k(const int* __restrict__ pk,
                                           const float* __restrict__ cg,
                                           const int* __restrict__ lengths,
                                           float* __restrict__ out) {
  int b = blockIdx.x;
  int lane = threadIdx.x;
  __shared__ int pks[TT + 1];
  __shared__ int bs[TT];
  __shared__ int ts[TT];

  const int* pb = pk + (size_t)b * (TT + 1);
  for (int k = lane; k <= TT; k += 64) pks[k] = pb[k];
  __syncthreads();

  int len = lengths[b];
  len = (len > TT) ? TT : (len < 0 ? 0 : len);
  int cnt = 0;
  if (lane == 0) {
    int st = len;
    while (st > 0 && cnt < TT) {
      int e = pks[st];
      bs[cnt] = st;
      ts[cnt] = e & 255;
      st = e >> 8;            // prev < st, strictly decreasing
      ++cnt;
    }
  }
  cnt = __shfl(cnt, 0);
  __syncthreads();

  float* bout = out + b * TT;
  float* tout = out + MM + b * TT;
  for (int k = lane; k < TT; k += 64) {
    bout[k] = (k < cnt) ? (float)bs[cnt - 1 - k] : 0.f;
    tout[k] = (k < cnt) ? (float)ts[cnt - 1 - k] : 0.f;
  }
  if (lane == 0) {
    out[2 * MM + b] = (float)cnt;                       // counts
    out[2 * MM + BB + b] = cg[(size_t)b * (TT + 1) + len]; // final cost
  }
}

// ---------------------------------------------------------------------------
extern "C" void kernel_launch(void* const* d_in, const int* in_sizes, int n_in,
                              void* d_out, int out_size, void* d_ws, size_t ws_size,
                              hipStream_t stream) {
  const float* reps = (const float*)d_in[0];
  const float* cb   = (const float*)d_in[1];
  const int* lengths = (const int*)d_in[2];
  float* out = (float*)d_out;

  char* ws = (char*)d_ws;
  float* r2 = (float*)ws;                                    // 64 KB
  float* c2 = (float*)(ws + 65536);                          // 4 KB slot
  char* p = ws + 69632;
  float* dmat = (float*)p;              p += (size_t)MM * VV * 4;       // 16 MB
  float* Wv   = (float*)p;              p += (size_t)MM * 64 * 4;       // 4 MB
  unsigned char* WI = (unsigned char*)p; p += (size_t)MM * 64;          // 1 MB
  float* cg   = (float*)p;              p += (size_t)BB * (TT + 1) * 4; // 65.6 KB
  int* pk     = (int*)p;                                                // 65.6 KB

  norms_k<<<(MM + VV) / 4, 256, 0, stream>>>(reps, cb, r2, c2);
  gemm_k<<<dim3(VV / 64, MM / 64), 256, 0, stream>>>(reps, cb, r2, c2, dmat);
  w_k<<<BB * (TT / 64), 256, 0, stream>>>(dmat, Wv, WI);
  dp_seq<<<BB, 64, 0, stream>>>(Wv, cg);
  prev_k<<<MM / 4, 256, 0, stream>>>(Wv, WI, cg, pk);
  bt_k<<<BB, 64, 0, stream>>>(pk, cg, lengths, out);
}

// Round 4
// 337.853 us; speedup vs baseline: 1.4935x; 1.2392x over previous
//
#include <hip/hip_runtime.h>

#define BB 16
#define TT 1024
#define DD 512
#define VV 256
#define MM (BB*TT)

#define DPINF 1e30f

// DPP min-reduce step; old = same reg -> identity for lanes with no source
#define DPP_MIN_STEP(m, CTRL) { \
  int _t = __builtin_amdgcn_update_dpp(__float_as_int(m), __float_as_int(m), CTRL, 0xF, 0xF, false); \
  m = fminf(m, __int_as_float(_t)); }

// full 64-lane min into lane 63: row_shr 1,2,4,8 then row_bcast15, row_bcast31
#define DPP_MIN_REDUCE(m) \
  DPP_MIN_STEP(m, 0x111); DPP_MIN_STEP(m, 0x112); DPP_MIN_STEP(m, 0x114); \
  DPP_MIN_STEP(m, 0x118); DPP_MIN_STEP(m, 0x142); DPP_MIN_STEP(m, 0x143);

// ---------------------------------------------------------------------------
// Kernel 1: row norms of reps (r2[16384]) and codebook (c2[256]); 1 wave/row
// ---------------------------------------------------------------------------
__global__ __launch_bounds__(256) void norms_k(const float* __restrict__ reps,
                                               const float* __restrict__ cb,
                                               float* __restrict__ r2,
                                               float* __restrict__ c2) {
  int row = blockIdx.x * 4 + (threadIdx.x >> 6);
  int lane = threadIdx.x & 63;
  const float* src;
  float* dst;
  if (row < MM) {
    src = reps + (size_t)row * DD;
    dst = r2 + row;
  } else {
    int r = row - MM;
    if (r >= VV) return;
    src = cb + (size_t)r * DD;
    dst = c2 + r;
  }
  const float4* s4 = (const float4*)src;
  float4 a = s4[lane];
  float4 b = s4[lane + 64];
  float s = a.x*a.x + a.y*a.y + a.z*a.z + a.w*a.w
          + b.x*b.x + b.y*b.y + b.z*b.z + b.w*b.w;
#pragma unroll
  for (int off = 1; off < 64; off <<= 1) s += __shfl_xor(s, off);
  if (lane == 0) *dst = s;
}

// ---------------------------------------------------------------------------
// Kernel 2: d[m][v] = r2[m] - 2*dot(reps[m], cb[v]) + c2[v]
// fp32 tiled GEMM: 64x64 tile, BK=32, 256 threads, 4x4 micro-tile
// ---------------------------------------------------------------------------
__global__ __launch_bounds__(256) void gemm_k(const float* __restrict__ reps,
                                              const float* __restrict__ cb,
                                              const float* __restrict__ r2,
                                              const float* __restrict__ c2,
                                              float* __restrict__ dmat) {
  __shared__ __align__(16) float As[32][68];
  __shared__ __align__(16) float Bs[32][68];
  int tid = threadIdx.x;
  int m0 = blockIdx.y * 64, n0 = blockIdx.x * 64;
  int tx = tid & 15, ty = tid >> 4;
  int lrow = tid >> 3, lcol = tid & 7;
  float acc[4][4] = {{0.f}};
  const float* arow0 = reps + (size_t)(m0 + lrow) * DD + lcol * 4;
  const float* arow1 = arow0 + (size_t)32 * DD;
  const float* brow0 = cb + (size_t)(n0 + lrow) * DD + lcol * 4;
  const float* brow1 = brow0 + (size_t)32 * DD;

  for (int k0 = 0; k0 < DD; k0 += 32) {
    float4 a0 = *(const float4*)(arow0 + k0);
    float4 a1 = *(const float4*)(arow1 + k0);
    float4 b0 = *(const float4*)(brow0 + k0);
    float4 b1 = *(const float4*)(brow1 + k0);
    __syncthreads();
    int kc = lcol * 4;
    As[kc+0][lrow] = a0.x; As[kc+1][lrow] = a0.y; As[kc+2][lrow] = a0.z; As[kc+3][lrow] = a0.w;
    As[kc+0][lrow+32] = a1.x; As[kc+1][lrow+32] = a1.y; As[kc+2][lrow+32] = a1.z; As[kc+3][lrow+32] = a1.w;
    Bs[kc+0][lrow] = b0.x; Bs[kc+1][lrow] = b0.y; Bs[kc+2][lrow] = b0.z; Bs[kc+3][lrow] = b0.w;
    Bs[kc+0][lrow+32] = b1.x; Bs[kc+1][lrow+32] = b1.y; Bs[kc+2][lrow+32] = b1.z; Bs[kc+3][lrow+32] = b1.w;
    __syncthreads();
#pragma unroll
    for (int kk = 0; kk < 32; ++kk) {
      float4 av = *(const float4*)&As[kk][ty * 4];
      float4 bv = *(const float4*)&Bs[kk][tx * 4];
      float aa[4] = {av.x, av.y, av.z, av.w};
      float bb[4] = {bv.x, bv.y, bv.z, bv.w};
#pragma unroll
      for (int i = 0; i < 4; ++i)
#pragma unroll
        for (int j = 0; j < 4; ++j)
          acc[i][j] += aa[i] * bb[j];
    }
  }

  int gm = m0 + ty * 4, gn = n0 + tx * 4;
  float cc[4] = {c2[gn], c2[gn+1], c2[gn+2], c2[gn+3]};
#pragma unroll
  for (int i = 0; i < 4; ++i) {
    float rv = r2[gm + i];
    float4 o;
    o.x = fmaf(-2.f, acc[i][0], rv + cc[0]);
    o.y = fmaf(-2.f, acc[i][1], rv + cc[1]);
    o.z = fmaf(-2.f, acc[i][2], rv + cc[2]);
    o.w = fmaf(-2.f, acc[i][3], rv + cc[3]);
    *(float4*)&dmat[(size_t)(gm + i) * VV + gn] = o;
  }
}

// ---------------------------------------------------------------------------
// Kernel 3: W[t][i] = min_v sum_{f=s+1..t} d[f][v], s = t-64+i.
// One block per (batch, 64-t chunk, v-half-of-128). Grid 512, 2 blocks/CU.
// Phase 1: PARALLEL window cumsum build: thread (c,g) [8 chunks x 32 f4-groups]
//   loads its 16 frame rows to regs, serial-sums in regs, writes chunk total;
//   barrier; adds prefix of preceding chunk totals; writes 16 cumsum rows.
// Phase 2: lane-private v-scan (as round 3), single half.
// Output layout [t][lane][2]: halves combined downstream (min / tie->half0).
// ---------------------------------------------------------------------------
__global__ __launch_bounds__(256) void w_k(const float* __restrict__ dmat,
                                           float* __restrict__ Wv2,
                                           unsigned char* __restrict__ WI2) {
  __shared__ __align__(16) float CL[128 * 128];
  __shared__ __align__(16) float TOT[8 * 128];
  int bx = blockIdx.x;
  int b = bx >> 5;
  int chunk = (bx >> 1) & 15;
  int half = bx & 1;
  int t1 = 1 + (chunk << 6);             // block covers t in [t1, t1+63]
  int tid = threadIdx.x;
  int wv = tid >> 6, lane = tid & 63;

  // ---- Phase 1: parallel cumsum build ----
  {
    int c = tid >> 5;          // 16-frame chunk 0..7
    int g = tid & 31;          // float4 group within half
    const float* base = dmat + (size_t)b * TT * VV + (half << 7) + (g << 2);
    float4 rr[16];
    float4 run = make_float4(0.f, 0.f, 0.f, 0.f);
#pragma unroll
    for (int j = 1; j <= 16; ++j) {
      int k = (c << 4) + j;
      int f = t1 - 64 + k;                 // frame for cumsum row k
      bool valid = (k <= 127) && (f >= 1) && (f <= TT);
      int fc = valid ? f : 1;
      float4 dv = *(const float4*)(base + (size_t)(fc - 1) * VV);
      if (!valid) dv = make_float4(0.f, 0.f, 0.f, 0.f);
      run.x += dv.x; run.y += dv.y; run.z += dv.z; run.w += dv.w;
      rr[j - 1] = run;
    }
    *(float4*)&TOT[c * 128 + (g << 2)] = run;
    if (c == 0) *(float4*)&CL[0 * 128 + (g << 2)] = make_float4(0.f, 0.f, 0.f, 0.f);
    __syncthreads();
    float4 off = make_float4(0.f, 0.f, 0.f, 0.f);
#pragma unroll
    for (int cc = 0; cc < 7; ++cc) {
      if (cc < c) {
        float4 tv = *(const float4*)&TOT[cc * 128 + (g << 2)];
        off.x += tv.x; off.y += tv.y; off.z += tv.z; off.w += tv.w;
      }
    }
#pragma unroll
    for (int j = 1; j <= 16; ++j) {
      int k = (c << 4) + j;
      if (k <= 127) {
        float4 s = rr[j - 1];
        s.x += off.x; s.y += off.y; s.z += off.z; s.w += off.w;
        *(float4*)&CL[k * 128 + ((g ^ (k & 31)) << 2)] = s;
      }
    }
  }
  __syncthreads();

  // ---- Phase 2: lane-private scan over this half's 128 v ----
  float bw[16];
  int ba[16];
#pragma unroll
  for (int j = 0; j < 16; ++j) { bw[j] = 1e38f; ba[j] = 0; }

#pragma unroll
  for (int j = 0; j < 16; ++j) {
    int dt = (j << 2) + wv;           // 0..63
    int ks = dt + lane;               // row of C_s (s = t-64+lane)
    int kt = dt + 64;                 // row of C_t
    const float* rs = &CL[ks * 128];
    const float* rt = &CL[kt * 128];
    int ksm = ks & 31, ktm = kt & 31;
    float bv = bw[j];
    int bi = ba[j];
#pragma unroll 4
    for (int g = 0; g < 32; ++g) {
      float4 a = *(const float4*)&rs[(g ^ ksm) << 2];
      float4 t4 = *(const float4*)&rt[(g ^ ktm) << 2];
      int v0 = (g << 2);
      float s0 = t4.x - a.x; if (s0 < bv) { bv = s0; bi = v0; }
      float s1 = t4.y - a.y; if (s1 < bv) { bv = s1; bi = v0 + 1; }
      float s2 = t4.z - a.z; if (s2 < bv) { bv = s2; bi = v0 + 2; }
      float s3 = t4.w - a.w; if (s3 < bv) { bv = s3; bi = v0 + 3; }
    }
    bw[j] = bv; ba[j] = bi;
  }

#pragma unroll
  for (int j = 0; j < 16; ++j) {
    int t = t1 + (j << 2) + wv;
    size_t idx = (((size_t)b * TT + (t - 1)) * 64 + lane) * 2 + half;
    Wv2[idx] = bw[j];
    WI2[idx] = (unsigned char)ba[j];   // v within half; half1 adds 128 at use
  }
}

// ---------------------------------------------------------------------------
// Kernel 4a: sequential DP, min VALUE only. One wave per batch.
// Lane l holds costs[s] for s == l (mod 64). Per step: add -> 6 dependent
// DPP mins -> readlane -> cndmask. Half-combine (fminf) is in the prefetch,
// off the critical chain.
// ---------------------------------------------------------------------------
__global__ __launch_bounds__(64) void dp_seq(const float* __restrict__ Wv2,
                                             float* __restrict__ cg) {
  int b = blockIdx.x;
  int lane = threadIdx.x;
  const float2* Wb = (const float2*)(Wv2 + (size_t)b * TT * 128);
  float* cgb = cg + (size_t)b * (TT + 1);
  float cs = (lane == 0) ? 0.f : DPINF;
  if (lane == 0) cgb[0] = 0.f;

  auto rowload = [&](int tt) -> float {
    int cr = (tt <= TT) ? (tt - 1) : (TT - 1);
    float2 w2 = Wb[cr * 64 + ((lane - tt) & 63)];
    return fminf(w2.x, w2.y);
  };

  auto step = [&](int t, float w) {
    float m = cs + w;
    DPP_MIN_REDUCE(m);
    float mf = __int_as_float(__builtin_amdgcn_readlane(__float_as_int(m), 63));
    if (lane == 63) cgb[t] = m;        // lane 63 holds the full min in VGPR
    cs = (lane == (t & 63)) ? mf : cs; // lane (t&63) now holds costs[t]
  };

  float a0 = rowload(1), a1 = rowload(2), a2 = rowload(3), a3 = rowload(4);
  float a4 = rowload(5), a5 = rowload(6), a6 = rowload(7), a7 = rowload(8);
  for (int t = 1; t <= TT; t += 4) {
    float n0 = rowload(t + 8);
    float n1 = rowload(t + 9);
    float n2 = rowload(t + 10);
    float n3 = rowload(t + 11);
    step(t, a0);
    step(t + 1, a1);
    step(t + 2, a2);
    step(t + 3, a3);
    a0 = a4; a1 = a5; a2 = a6; a3 = a7;
    a4 = n0; a5 = n1; a6 = n2; a7 = n3;
  }
}

// ---------------------------------------------------------------------------
// Kernel 4b: parallel argmin. One wave per t: recompute total = cg[s]+W[t][i]
// (bit-identical to dp_seq's sums), find first-min -> prev, tok.
// Half-combine: value = min, token = half0 on tie (lowest v wins).
// ---------------------------------------------------------------------------
__global__ __launch_bounds__(256) void prev_k(const float* __restrict__ Wv2,
                                              const unsigned char* __restrict__ WI2,
                                              const float* __restrict__ cg,
                                              int* __restrict__ pk) {
  int row = blockIdx.x * 4 + (threadIdx.x >> 6);   // row in [0, BB*TT)
  int lane = threadIdx.x & 63;
  int b = row >> 10;
  int t = (row & 1023) + 1;
  int s = t - 64 + lane;
  size_t idx = (size_t)row * 64 + lane;
  float2 w2 = ((const float2*)Wv2)[idx];
  uchar2 i2 = ((const uchar2*)WI2)[idx];
  bool h0 = (w2.x <= w2.y);
  float w = h0 ? w2.x : w2.y;
  int wi = h0 ? (int)i2.x : ((int)i2.y + 128);
  int sc = (s < 0) ? 0 : s;
  float c = cg[(size_t)b * (TT + 1) + sc];
  float total = (s >= 0) ? (c + w) : DPINF;
  float m = total;
  DPP_MIN_REDUCE(m);
  float mf = __int_as_float(__builtin_amdgcn_readlane(__float_as_int(m), 63));
  unsigned long long msk = __ballot(total == mf);
  int iwin = __builtin_ctzll(msk);                 // smallest i = smallest s (ref tie-break)
  int tok = __builtin_amdgcn_readlane(wi, iwin) & 255;
  int prev = t - 64 + iwin;
  if (lane == 0) pk[(size_t)b * (TT + 1) + t] = (prev << 8) | tok;
}

// ---------------------------------------------------------------------------
// Kernel 4c: backtrack + outputs. One wave per batch; packed prev/tok walk
// in LDS; float32-encoded outputs (harness reads whole d_out as float32).
// ---------------------------------------------------------------------------
__global__ __launch_bounds__(64) void bt_k(const int* __restrict__ pk,
                                           const float* __restrict__ cg,
                                           const int* __restrict__ lengths,
                                           float* __restrict__ out) {
  int b = blockIdx.x;
  int lane = threadIdx.x;
  __shared__ int pks[TT + 1];
  __shared__ int bs[TT];
  __shared__ int ts[TT];

  const int* pb = pk + (size_t)b * (TT + 1);
  for (int k = lane; k <= TT; k += 64) pks[k] = pb[k];
  __syncthreads();

  int len = lengths[b];
  len = (len > TT) ? TT : (len < 0 ? 0 : len);
  int cnt = 0;
  if (lane == 0) {
    int st = len;
    while (st > 0 && cnt < TT) {
      int e = pks[st];
      bs[cnt] = st;
      ts[cnt] = e & 255;
      st = e >> 8;            // prev < st, strictly decreasing
      ++cnt;
    }
  }
  cnt = __shfl(cnt, 0);
  __syncthreads();

  float* bout = out + b * TT;
  float* tout = out + MM + b * TT;
  for (int k = lane; k < TT; k += 64) {
    bout[k] = (k < cnt) ? (float)bs[cnt - 1 - k] : 0.f;
    tout[k] = (k < cnt) ? (float)ts[cnt - 1 - k] : 0.f;
  }
  if (lane == 0) {
    out[2 * MM + b] = (float)cnt;                          // counts
    out[2 * MM + BB + b] = cg[(size_t)b * (TT + 1) + len]; // final cost
  }
}

// ---------------------------------------------------------------------------
extern "C" void kernel_launch(void* const* d_in, const int* in_sizes, int n_in,
                              void* d_out, int out_size, void* d_ws, size_t ws_size,
                              hipStream_t stream) {
  const float* reps = (const float*)d_in[0];
  const float* cb   = (const float*)d_in[1];
  const int* lengths = (const int*)d_in[2];
  float* out = (float*)d_out;

  char* ws = (char*)d_ws;
  float* r2 = (float*)ws;                                    // 64 KB
  float* c2 = (float*)(ws + 65536);                          // 4 KB slot
  char* p = ws + 69632;
  float* dmat = (float*)p;               p += (size_t)MM * VV * 4;       // 16 MB
  float* Wv2  = (float*)p;               p += (size_t)MM * 128 * 4;      // 8 MB
  unsigned char* WI2 = (unsigned char*)p; p += (size_t)MM * 128;         // 2 MB
  float* cg   = (float*)p;               p += (size_t)BB * (TT + 1) * 4; // 65.6 KB
  int* pk     = (int*)p;                                                 // 65.6 KB

  norms_k<<<(MM + VV) / 4, 256, 0, stream>>>(reps, cb, r2, c2);
  gemm_k<<<dim3(VV / 64, MM / 64), 256, 0, stream>>>(reps, cb, r2, c2, dmat);
  w_k<<<BB * (TT / 64) * 2, 256, 0, stream>>>(dmat, Wv2, WI2);
  dp_seq<<<BB, 64, 0, stream>>>(Wv2, cg);
  prev_k<<<MM / 4, 256, 0, stream>>>(Wv2, WI2, cg, pk);
  bt_k<<<BB, 64, 0, stream>>>(pk, cg, lengths, out);
}